// Round 1
// baseline (3175.289 us; speedup 1.0000x reference)
//
#include <hip/hip_runtime.h>
#include <cmath>

#define TT 256   // time steps
#define BB 256   // batch
#define KD 192   // 64 x + 64 prevH + 64 dH
#define GD 512   // 4*STATE
#define SD 128   // STATE
#define HD 64    // H
#define OD 64    // OUT

__device__ __forceinline__ float sigm(float x){
  return 1.0f / (1.0f + __expf(-x));
}

extern "C" __global__ void __launch_bounds__(512, 2)
s2_stack_kernel(const float* __restrict__ xin,
                const float* __restrict__ W,
                const float* __restrict__ bias,
                const float* __restrict__ Wa,
                const float* __restrict__ ba,
                float* __restrict__ out,
                float* __restrict__ ws)
{
  const int b   = blockIdx.x;
  const int tid = threadIdx.x;

  __shared__ __align__(16) float sh_xh[KD];   // [x | prevH | dH]
  __shared__ float sh_gates[GD];
  __shared__ float sh_hbuf[12*HD];            // dilated h circular buffer (max d=12)
  __shared__ float sh_cbuf[12*SD];            // dilated c circular buffer
  __shared__ float sh_fin[OD];
  __shared__ float sh_ba[OD];
  __shared__ float sh_wa[OD*OD];              // transposed: sh_wa[k*64+i] = Wa[i][k]

  // bufA: ws scratch, per-block [T][64], stride 64.
  // bufB: lives inside d_out (element (t,j) at out[(t*BB+b)*OD+j]) — holds L1 output
  //       (block-skip) until the fused projection overwrites each row after use.
  volatile float* bufA = (float*)ws + (size_t)b * (TT*OD);
  float* outbB = out + (size_t)b * OD;            // stride per t: BB*OD
  const float* ginx = xin + (size_t)b * OD;       // stride per t: BB*OD

  float w[KD];  // this thread's weight row, register-resident

  #pragma unroll 1
  for (int l = 0; l < 4; ++l) {
    const int d = (l==0) ? 1 : ((l==1) ? 3 : ((l==2) ? 6 : 12));

    // ---- load this layer's weight row into registers (from L2/L3) ----
    const float4* wrow = (const float4*)(W + ((size_t)l*GD + tid)*KD);
    #pragma unroll
    for (int q = 0; q < KD/4; ++q) {
      float4 v = wrow[q];
      w[4*q+0]=v.x; w[4*q+1]=v.y; w[4*q+2]=v.z; w[4*q+3]=v.w;
    }
    const float bv = bias[l*GD + tid];

    // ---- init xh: x_0 in [0..63], zeros in [64..191] ----
    if (tid < 2*HD) sh_xh[HD + tid] = 0.0f;
    float xreg = 0.f, skipreg = 0.f;
    if (tid < OD) {
      float x0, x1;
      if (l == 0)      { x0 = ginx[tid];  x1 = ginx[(size_t)BB*OD + tid]; }
      else if (l == 2) { x0 = outbB[tid]; x1 = outbB[(size_t)BB*OD + tid]; }
      else             { x0 = bufA[tid];  x1 = bufA[OD + tid]; }
      sh_xh[tid] = x0;
      xreg = x1;                           // x_1, written into xh at t=0 phase B
      if (l == 3) skipreg = outbB[tid];    // skip[0]
    }
    if (l == 3) {
      for (int e = tid; e < OD*OD; e += 512) {
        int i = e >> 6, k = e & 63;
        sh_wa[k*OD + i] = Wa[e];
      }
      if (tid < OD) sh_ba[tid] = ba[tid];
    }
    float cprev = 0.f;
    int idx = 0;                            // t % d, carried
    __syncthreads();

    #pragma unroll 1
    for (int t = 0; t < TT; ++t) {
      // ================= phase A: gates[tid] = bv + W[tid,:] . xh =================
      float a0=0.f, a1=0.f, a2=0.f, a3=0.f;
      const float4* xh4 = (const float4*)sh_xh;
      #pragma unroll
      for (int q = 0; q < KD/4; ++q) {
        float4 v = xh4[q];                  // broadcast ds_read_b128
        a0 = fmaf(w[4*q+0], v.x, a0);
        a1 = fmaf(w[4*q+1], v.y, a1);
        a2 = fmaf(w[4*q+2], v.z, a2);
        a3 = fmaf(w[4*q+3], v.w, a3);
      }
      sh_gates[tid] = bv + ((a0+a1)+(a2+a3));
      __syncthreads();

      // ================= phase B: elementwise state update (threads 0..127) =======
      const int idx2 = (idx+1 == d) ? 0 : (idx+1);
      if (tid < SD) {
        const int j = tid;
        const float g0 = sh_gates[j];
        const float g1 = sh_gates[SD + j];
        const float g2 = sh_gates[2*SD + j];
        const float g3 = sh_gates[3*SD + j];
        const float f  = sigm(g0 + 1.0f);
        const float ns = tanhf(g1);
        const float al = sigm(g2);
        const float o  = sigm(g3);
        const float dC = sh_cbuf[idx*SD + j];
        const float wC = (t >= d) ? fmaf(al, cprev - dC, dC) : cprev;  // al*c+(1-al)*dC
        const float nc = (t > 0)  ? fmaf(f, wC - ns, ns) : ns;          // f*wC+(1-f)*ns
        const float whole = o * nc;
        sh_cbuf[idx*SD + j] = nc;
        cprev = nc;
        if (tid < OD) {
          // ---- output dims 0..63 ----
          if (l == 3) {
            sh_fin[j] = whole + skipreg;   // L3 out + L1 out (block skip)
            skipreg = (t+1 < TT) ? outbB[(size_t)(t+1)*BB*OD + j] : 0.f;
          } else if (l == 1) {
            outbB[(size_t)t*BB*OD + j] = whole;     // L1 out -> bufB (in d_out)
          } else {
            bufA[t*OD + j] = whole;                 // L0/L2 out -> bufA (ws)
          }
          // ---- next-step x into xh, prefetch one step further ----
          sh_xh[j] = xreg;
          if (t+2 < TT) {
            if (l == 0)      xreg = ginx[(size_t)(t+2)*BB*OD + j];
            else if (l == 2) xreg = outbB[(size_t)(t+2)*BB*OD + j];
            else             xreg = bufA[(t+2)*OD + j];
          } else xreg = 0.f;
        } else {
          // ---- h dims 64..127 ----
          const int jj = tid - HD;
          sh_hbuf[idx*HD + jj] = whole;             // h_t into slot t%d
          sh_xh[HD + jj] = whole;                   // prevH for step t+1
          float dh;
          if (t+1 >= d) dh = (d == 1) ? whole : sh_hbuf[idx2*HD + jj]; // h_{t+1-d}
          else          dh = whole;                 // falls back to prevH
          sh_xh[2*HD + jj] = dh;
        }
      }
      idx = idx2;
      __syncthreads();

      // ================= phase C (layer 3 only): fused y = fin @ Wa^T + ba ========
      if (l == 3 && tid < OD) {
        float p0 = sh_ba[tid], p1 = 0.f, p2 = 0.f, p3 = 0.f;
        #pragma unroll
        for (int k = 0; k < OD; k += 4) {
          p0 = fmaf(sh_fin[k+0], sh_wa[(k+0)*OD + tid], p0);
          p1 = fmaf(sh_fin[k+1], sh_wa[(k+1)*OD + tid], p1);
          p2 = fmaf(sh_fin[k+2], sh_wa[(k+2)*OD + tid], p2);
          p3 = fmaf(sh_fin[k+3], sh_wa[(k+3)*OD + tid], p3);
        }
        out[((size_t)t*BB + b)*OD + tid] = ((p0+p1)+(p2+p3));
      }
    } // t

    __threadfence();    // make ws / d_out writes visible before next layer reads
    __syncthreads();
  } // l
}

extern "C" void kernel_launch(void* const* d_in, const int* in_sizes, int n_in,
                              void* d_out, int out_size, void* d_ws, size_t ws_size,
                              hipStream_t stream)
{
  const float* x  = (const float*)d_in[0];
  const float* W  = (const float*)d_in[1];
  const float* bb = (const float*)d_in[2];
  const float* Wa = (const float*)d_in[3];
  const float* ba = (const float*)d_in[4];
  float* out = (float*)d_out;
  float* ws  = (float*)d_ws;

  hipLaunchKernelGGL(s2_stack_kernel, dim3(BB), dim3(512), 0, stream,
                     x, W, bb, Wa, ba, out, ws);
}

// Round 3
// 2255.542 us; speedup vs baseline: 1.4078x; 1.4078x over previous
//
#include <hip/hip_runtime.h>
#include <cmath>

#define TT 256   // time steps
#define BB 256   // batch
#define KD 192   // 64 x + 64 prevH + 64 dH
#define GD 512   // 4*STATE
#define SD 128   // STATE
#define HD 64    // H
#define OD 64    // OUT

__device__ __forceinline__ float rl(float x, int k) {
  return __int_as_float(__builtin_amdgcn_readlane(__float_as_int(x), k));
}
__device__ __forceinline__ float fast_rcp(float x) {
  return __builtin_amdgcn_rcpf(x);
}
__device__ __forceinline__ float sigm(float x) {
  // 1/(1+exp(-x)); safe at extremes (exp->inf => rcp(inf)=0; exp->0 => 1)
  return fast_rcp(1.0f + __expf(-x));
}
__device__ __forceinline__ float fast_tanh(float x) {
  x = fminf(15.0f, fmaxf(-15.0f, x));
  float e = __expf(-2.0f * x);
  return (1.0f - e) * fast_rcp(1.0f + e);
}

extern "C" __global__ void
__attribute__((amdgpu_flat_work_group_size(512, 512), amdgpu_waves_per_eu(2, 2)))
s2_stack_kernel(const float* __restrict__ xin,
                const float* __restrict__ W,
                const float* __restrict__ bias,
                const float* __restrict__ Wa,
                const float* __restrict__ ba,
                float* __restrict__ out,
                float* __restrict__ ws)
{
  const int b    = blockIdx.x;
  const int tid  = threadIdx.x;
  const int lane = tid & 63;

  __shared__ __align__(16) float sh_xh[KD];   // [x | prevH | dH]
  __shared__ float sh_gates[GD];
  __shared__ float sh_hbuf[12*HD];            // dilated h circular buffer (max d=12)
  __shared__ float sh_cbuf[12*SD];            // dilated c circular buffer
  __shared__ float sh_fin[OD];
  __shared__ float sh_ba[OD];
  __shared__ float sh_wa[OD*OD];              // transposed: sh_wa[k*64+i] = Wa[i][k]

  // bufA: ws scratch, per-block [T][64], stride 64.
  // bufB: lives inside d_out (element (t,j) at out[(t*BB+b)*OD+j]) — holds L1 output
  //       (block-skip) until the fused projection overwrites each row after use.
  volatile float* bufA = (float*)ws + (size_t)b * (TT*OD);
  float* outbB = out + (size_t)b * OD;            // stride per t: BB*OD
  const float* ginx = xin + (size_t)b * OD;       // stride per t: BB*OD

  float w[KD];  // this thread's weight row, register-resident

  #pragma unroll 1
  for (int l = 0; l < 4; ++l) {
    const int d = (l==0) ? 1 : ((l==1) ? 3 : ((l==2) ? 6 : 12));

    // ---- load this layer's weight row into registers (from L2/L3) ----
    const float4* wrow = (const float4*)(W + ((size_t)l*GD + tid)*KD);
    #pragma unroll
    for (int q = 0; q < KD/4; ++q) {
      float4 v = wrow[q];
      w[4*q+0]=v.x; w[4*q+1]=v.y; w[4*q+2]=v.z; w[4*q+3]=v.w;
    }
    const float bv = bias[l*GD + tid];

    // ---- init xh: x_0 in [0..63], zeros in [64..191] ----
    if (tid < 2*HD) sh_xh[HD + tid] = 0.0f;
    float xreg = 0.f, skipreg = 0.f;
    if (tid < OD) {
      float x0, x1;
      if (l == 0)      { x0 = ginx[tid];  x1 = ginx[(size_t)BB*OD + tid]; }
      else if (l == 2) { x0 = outbB[tid]; x1 = outbB[(size_t)BB*OD + tid]; }
      else             { x0 = bufA[tid];  x1 = bufA[OD + tid]; }
      sh_xh[tid] = x0;
      xreg = x1;                           // x_1, written into xh at t=0 phase B
      if (l == 3) skipreg = outbB[tid];    // skip[0]
    }
    if (l == 3) {
      for (int e = tid; e < OD*OD; e += 512) {
        int i = e >> 6, k = e & 63;
        sh_wa[k*OD + i] = Wa[e];
      }
      if (tid < OD) sh_ba[tid] = ba[tid];
    }
    float cprev = 0.f;
    int idx = 0;                            // t % d, carried
    __syncthreads();

    #pragma unroll 1
    for (int t = 0; t < TT; ++t) {
      // ===== phase A: gates[tid] = bv + W[tid,:] . xh, xh via v_readlane =====
      // lane k of every wave holds xh[k], xh[64+k], xh[128+k]
      float xh0 = sh_xh[lane];
      float xh1 = sh_xh[64 + lane];
      float xh2 = sh_xh[128 + lane];
      float a0=0.f, a1=0.f, a2=0.f, a3=0.f, a4=0.f, a5=0.f;
      #pragma unroll
      for (int k = 0; k < 64; k += 2) {
        float s00 = rl(xh0, k), s01 = rl(xh0, k+1);
        float s10 = rl(xh1, k), s11 = rl(xh1, k+1);
        float s20 = rl(xh2, k), s21 = rl(xh2, k+1);
        a0 = fmaf(s00, w[k],      a0);
        a1 = fmaf(s01, w[k+1],    a1);
        a2 = fmaf(s10, w[64+k],   a2);
        a3 = fmaf(s11, w[64+k+1], a3);
        a4 = fmaf(s20, w[128+k],  a4);
        a5 = fmaf(s21, w[128+k+1],a5);
      }
      sh_gates[tid] = bv + (((a0+a1)+(a2+a3))+(a4+a5));
      __syncthreads();

      // ===== phase B: elementwise state update (threads 0..127) =====
      const int idx2 = (idx+1 == d) ? 0 : (idx+1);
      if (tid < SD) {
        const int j = tid;
        const float g0 = sh_gates[j];
        const float g1 = sh_gates[SD + j];
        const float g2 = sh_gates[2*SD + j];
        const float g3 = sh_gates[3*SD + j];
        const float f  = sigm(g0 + 1.0f);
        const float ns = fast_tanh(g1);
        const float al = sigm(g2);
        const float o  = sigm(g3);
        const float dC = sh_cbuf[idx*SD + j];
        const float wC = (t >= d) ? fmaf(al, cprev - dC, dC) : cprev;  // al*c+(1-al)*dC
        const float nc = (t > 0)  ? fmaf(f, wC - ns, ns) : ns;          // f*wC+(1-f)*ns
        const float whole = o * nc;
        sh_cbuf[idx*SD + j] = nc;
        cprev = nc;
        if (tid < OD) {
          // ---- output dims 0..63 ----
          if (l == 3) {
            sh_fin[j] = whole + skipreg;   // L3 out + L1 out (block skip)
            skipreg = (t+1 < TT) ? outbB[(size_t)(t+1)*BB*OD + j] : 0.f;
          } else if (l == 1) {
            outbB[(size_t)t*BB*OD + j] = whole;     // L1 out -> bufB (in d_out)
          } else {
            bufA[t*OD + j] = whole;                 // L0/L2 out -> bufA (ws)
          }
          // ---- next-step x into xh, prefetch one step further ----
          sh_xh[j] = xreg;
          if (t+2 < TT) {
            if (l == 0)      xreg = ginx[(size_t)(t+2)*BB*OD + j];
            else if (l == 2) xreg = outbB[(size_t)(t+2)*BB*OD + j];
            else             xreg = bufA[(t+2)*OD + j];
          } else xreg = 0.f;
        } else {
          // ---- h dims 64..127 ----
          const int jj = tid - HD;
          sh_hbuf[idx*HD + jj] = whole;             // h_t into slot t%d
          sh_xh[HD + jj] = whole;                   // prevH for step t+1
          float dh;
          if (t+1 >= d) dh = (d == 1) ? whole : sh_hbuf[idx2*HD + jj]; // h_{t+1-d}
          else          dh = whole;                 // falls back to prevH
          sh_xh[2*HD + jj] = dh;
        }
      }
      idx = idx2;
      __syncthreads();

      // ===== phase C (layer 3 only): fused y = fin @ Wa^T + ba =====
      if (l == 3 && tid < OD) {
        float p0 = sh_ba[tid], p1 = 0.f, p2 = 0.f, p3 = 0.f;
        #pragma unroll
        for (int k = 0; k < OD; k += 4) {
          p0 = fmaf(sh_fin[k+0], sh_wa[(k+0)*OD + tid], p0);
          p1 = fmaf(sh_fin[k+1], sh_wa[(k+1)*OD + tid], p1);
          p2 = fmaf(sh_fin[k+2], sh_wa[(k+2)*OD + tid], p2);
          p3 = fmaf(sh_fin[k+3], sh_wa[(k+3)*OD + tid], p3);
        }
        out[((size_t)t*BB + b)*OD + tid] = ((p0+p1)+(p2+p3));
      }
    } // t

    __threadfence();    // make ws / d_out writes visible before next layer reads
    __syncthreads();
  } // l
}

extern "C" void kernel_launch(void* const* d_in, const int* in_sizes, int n_in,
                              void* d_out, int out_size, void* d_ws, size_t ws_size,
                              hipStream_t stream)
{
  const float* x  = (const float*)d_in[0];
  const float* W  = (const float*)d_in[1];
  const float* bb = (const float*)d_in[2];
  const float* Wa = (const float*)d_in[3];
  const float* ba = (const float*)d_in[4];
  float* out = (float*)d_out;
  float* ws  = (float*)d_ws;

  hipLaunchKernelGGL(s2_stack_kernel, dim3(BB), dim3(512), 0, stream,
                     x, W, bb, Wa, ba, out, ws);
}

// Round 4
// 1372.607 us; speedup vs baseline: 2.3133x; 1.6433x over previous
//
#include <hip/hip_runtime.h>
#include <cmath>

#define TT 256
#define KD 192

typedef _Float16 f16;
typedef _Float16 f16x4 __attribute__((ext_vector_type(4)));
typedef _Float16 f16x8 __attribute__((ext_vector_type(8)));
typedef float    f32x4 __attribute__((ext_vector_type(4)));

// XOR swizzle (f16-element units): spreads batch rows across LDS banks.
// XOR bits 3..5 (multiples of 8 f16 = 16B) -> preserves 8B alignment of 4-elem chunks.
#define SWZ(b,k) ((k) ^ (((b)&7)<<3))
#define MFMA16(a,bb,c) __builtin_amdgcn_mfma_f32_16x16x32_f16((a),(bb),(c),0,0,0)

__device__ __forceinline__ float sigm(float x){
  return __builtin_amdgcn_rcpf(1.0f + __expf(-x));
}
__device__ __forceinline__ float ftanh(float x){
  x = fminf(15.0f, fmaxf(-15.0f, x));
  float e = __expf(-2.0f*x);
  return (1.0f - e) * __builtin_amdgcn_rcpf(1.0f + e);
}

// One block = 16 batch elements. 8 waves. Wave w owns gate row-tiles
// {w, w+8, w+16, w+24} -> thread holds g0..g3 for states s0..s0+3, batch b.
// MFMA A-frag: A[i][k], i=lane&15, k=8*(lane>>4)+e. B-frag: B[k][col], col=lane&15.
// C/D: col=lane&15, row=4*(lane>>4)+reg  (verified layouts, learn_hip m89).
extern "C" __global__ void
__attribute__((amdgpu_flat_work_group_size(512,512), amdgpu_waves_per_eu(2,2)))
s2_mfma_kernel(const float* __restrict__ xin, const float* __restrict__ W,
               const float* __restrict__ bias, const float* __restrict__ Wa,
               const float* __restrict__ ba, float* __restrict__ out,
               f16* __restrict__ bufA, f16* __restrict__ bufB)
{
  const int tid  = threadIdx.x;
  const int wave = tid >> 6;
  const int lane = tid & 63;
  const int b    = lane & 15;          // batch within block (C-frag col)
  const int g4   = lane >> 4;          // row-quad within tile
  const int gb   = blockIdx.x * 16 + b;
  const int s0   = wave*16 + g4*4;     // first of this thread's 4 state dims

  __shared__ f16 sxh[2][16*KD];        // xh double-buffered: [batch][192] swizzled
  __shared__ f16 scb[12*16*128];       // c circular buffer (max d=12)
  __shared__ f16 shb[12*16*64];        // h circular buffer
  __shared__ f16 sfin[2][16*64];       // fin (L3 out + skip), double-buffered

  // ---- projection A-frags + bias (waves 0-3), loaded once ----
  f16x8 aP[2]; f32x4 cbP;
  if (wave < 4) {
    #pragma unroll
    for (int kt=0;kt<2;++kt) {
      const float* p = Wa + (size_t)(wave*16 + b)*64 + kt*32 + g4*8;
      float4 lo = *(const float4*)p, hi = *(const float4*)(p+4);
      f16x8 v;
      v[0]=(f16)lo.x; v[1]=(f16)lo.y; v[2]=(f16)lo.z; v[3]=(f16)lo.w;
      v[4]=(f16)hi.x; v[5]=(f16)hi.y; v[6]=(f16)hi.z; v[7]=(f16)hi.w;
      aP[kt]=v;
    }
    float4 bb4 = *(const float4*)(ba + s0);
    cbP[0]=bb4.x; cbP[1]=bb4.y; cbP[2]=bb4.z; cbP[3]=bb4.w;
  }

  f16x8 aW[4][6];      // W fragments: [gate][k-tile], 96 VGPRs
  f32x4 cb[4];         // bias as C-init frags

  #pragma unroll 1
  for (int l=0; l<4; ++l) {
    const int d = (l==0)?1:((l==1)?3:((l==2)?6:12));
    const float* Wl = W + (size_t)l*512*KD;
    #pragma unroll
    for (int q=0;q<4;++q) {
      const float* pr = Wl + (size_t)(128*q + 16*wave + b)*KD + g4*8;
      #pragma unroll
      for (int kt=0;kt<6;++kt) {
        float4 lo = *(const float4*)(pr + kt*32);
        float4 hi = *(const float4*)(pr + kt*32 + 4);
        f16x8 v;
        v[0]=(f16)lo.x; v[1]=(f16)lo.y; v[2]=(f16)lo.z; v[3]=(f16)lo.w;
        v[4]=(f16)hi.x; v[5]=(f16)hi.y; v[6]=(f16)hi.z; v[7]=(f16)hi.w;
        aW[q][kt]=v;
      }
      float4 b4 = *(const float4*)(bias + l*512 + 128*q + s0);
      cb[q][0]=b4.x; cb[q][1]=b4.y; cb[q][2]=b4.z; cb[q][3]=b4.w;
    }

    // ---- layer init: xh(t=0) = [x0 | 0 | 0]; prefetch x1 ----
    float4 xAf, xBf; f16x4 xAh, xBh, skA, skB;
    if (wave >= 4) {
      f16x4 zz = {(f16)0,(f16)0,(f16)0,(f16)0};
      *(f16x4*)&sxh[0][b*KD + SWZ(b, s0)]    = zz;   // prevH part (k=s0, 64..127)
      *(f16x4*)&sxh[0][b*KD + SWZ(b, s0+64)] = zz;   // dH part (128..191)
    } else {
      if (l==0) {
        float4 v0 = *(const float4*)(xin + ((size_t)gb)*64 + s0);
        f16x4 h; h[0]=(f16)v0.x; h[1]=(f16)v0.y; h[2]=(f16)v0.z; h[3]=(f16)v0.w;
        *(f16x4*)&sxh[0][b*KD + SWZ(b, s0)] = h;
        xAf = *(const float4*)(xin + ((size_t)256 + gb)*64 + s0);
      } else {
        const f16* src = (l==2) ? bufB : bufA;
        *(f16x4*)&sxh[0][b*KD + SWZ(b, s0)] = *(const f16x4*)(src + ((size_t)gb)*64 + s0);
        xAh = *(const f16x4*)(src + ((size_t)256 + gb)*64 + s0);
      }
      if (l==3) skA = *(const f16x4*)(bufB + ((size_t)gb)*64 + s0);
    }
    float cpr[4] = {0.f,0.f,0.f,0.f};
    int idx = 0;
    __syncthreads();

    #pragma unroll 1
    for (int t=0; t<TT; ++t) {
      const int p = t & 1;
      // ---- phase A: B-frag reads of xh(t) ----
      f16x8 bx[6];
      const f16* xrow = &sxh[p][b*KD];
      #pragma unroll
      for (int kt=0;kt<6;++kt)
        bx[kt] = *(const f16x8*)&xrow[SWZ(b, kt*32 + g4*8)];

      // ---- early prefetch issue (hidden under MFMA+phase B) ----
      if (wave < 4) {
        if (l==0) { if (t+2 < TT) xBf = *(const float4*)(xin + ((size_t)(t+2)*256 + gb)*64 + s0); }
        else {
          const f16* src = (l==2) ? bufB : bufA;
          if (t+2 < TT) xBh = *(const f16x4*)(src + ((size_t)(t+2)*256 + gb)*64 + s0);
        }
        if (l==3 && t+1 < TT) skB = *(const f16x4*)(bufB + ((size_t)(t+1)*256 + gb)*64 + s0);
      }

      // ---- fused projection for step t-1 (layer 3 only) ----
      if (l==3 && wave < 4 && t > 0) {
        const f16* fr = &sfin[p^1][b*64];
        f16x8 b0 = *(const f16x8*)&fr[SWZ(b, g4*8)];
        f16x8 b1 = *(const f16x8*)&fr[SWZ(b, 32 + g4*8)];
        f32x4 pa = cbP;
        pa = MFMA16(aP[0], b0, pa);
        pa = MFMA16(aP[1], b1, pa);
        float4 st; st.x=pa[0]; st.y=pa[1]; st.z=pa[2]; st.w=pa[3];
        *(float4*)(out + ((size_t)(t-1)*256 + gb)*64 + s0) = st;
      }

      // ---- gate MFMA: gates = W . xh + bias ----
      f32x4 a0=cb[0], a1=cb[1], a2=cb[2], a3=cb[3];
      #pragma unroll
      for (int kt=0;kt<6;++kt) {
        a0 = MFMA16(aW[0][kt], bx[kt], a0);
        a1 = MFMA16(aW[1][kt], bx[kt], a1);
        a2 = MFMA16(aW[2][kt], bx[kt], a2);
        a3 = MFMA16(aW[3][kt], bx[kt], a3);
      }

      // ---- phase B: in-register LSTM update (4 cells/thread) ----
      const int idx2 = (idx+1==d) ? 0 : idx+1;
      f16x4 dCv = *(const f16x4*)&scb[(idx*16+b)*128 + SWZ(b, s0)];
      float whole[4]; f16x4 ncv;
      #pragma unroll
      for (int r=0;r<4;++r) {
        float f  = sigm(a0[r] + 1.0f);
        float ns = ftanh(a1[r]);
        float al = sigm(a2[r]);
        float o  = sigm(a3[r]);
        float dC = (float)dCv[r];
        float wC = (t>=d) ? fmaf(al, cpr[r]-dC, dC) : cpr[r];
        float nc = (t>0)  ? fmaf(f, wC-ns, ns) : ns;
        whole[r] = o*nc; cpr[r] = nc; ncv[r] = (f16)nc;
      }
      *(f16x4*)&scb[(idx*16+b)*128 + SWZ(b, s0)] = ncv;   // own-address, no race

      if (wave >= 4) {
        // h dims 64..127: feed hbuf + xh(t+1) prevH/dH parts
        const int jj = s0 - 64;
        f16x4 hv;
        #pragma unroll
        for (int r=0;r<4;++r) hv[r]=(f16)whole[r];
        *(f16x4*)&shb[(idx*16+b)*64 + SWZ(b, jj)] = hv;
        *(f16x4*)&sxh[p^1][b*KD + SWZ(b, s0)] = hv;       // prevH for t+1
        f16x4 dhv = hv;                                    // t+1<d or d==1 fallback
        if (t+1 >= d && d > 1)
          dhv = *(const f16x4*)&shb[(idx2*16+b)*64 + SWZ(b, jj)];  // h_{t+1-d}
        *(f16x4*)&sxh[p^1][b*KD + SWZ(b, s0+64)] = dhv;   // dH for t+1
      } else {
        // out dims 0..63: emit layer output + stage x(t+1)
        f16x4 xv;
        if (l==0) { xv[0]=(f16)xAf.x; xv[1]=(f16)xAf.y; xv[2]=(f16)xAf.z; xv[3]=(f16)xAf.w; xAf = xBf; }
        else      { xv = xAh; xAh = xBh; }
        *(f16x4*)&sxh[p^1][b*KD + SWZ(b, s0)] = xv;
        if (l==3) {
          f16x4 fv;
          #pragma unroll
          for (int r=0;r<4;++r) fv[r] = (f16)(whole[r] + (float)skA[r]);
          *(f16x4*)&sfin[p][b*64 + SWZ(b, s0)] = fv;
          skA = skB;
        } else {
          f16* dst = (l==1) ? bufB : bufA;
          f16x4 ov;
          #pragma unroll
          for (int r=0;r<4;++r) ov[r]=(f16)whole[r];
          *(f16x4*)(dst + ((size_t)t*256 + gb)*64 + s0) = ov;
        }
      }
      idx = idx2;
      __syncthreads();   // single barrier per step (xh/fin double-buffered)
    } // t

    // epilogue projection for t = 255
    if (l==3 && wave < 4) {
      const f16* fr = &sfin[1][b*64];          // (TT-1)&1 == 1
      f16x8 b0 = *(const f16x8*)&fr[SWZ(b, g4*8)];
      f16x8 b1 = *(const f16x8*)&fr[SWZ(b, 32 + g4*8)];
      f32x4 pa = cbP;
      pa = MFMA16(aP[0], b0, pa);
      pa = MFMA16(aP[1], b1, pa);
      float4 st; st.x=pa[0]; st.y=pa[1]; st.z=pa[2]; st.w=pa[3];
      *(float4*)(out + ((size_t)(TT-1)*256 + gb)*64 + s0) = st;
    }

    __threadfence();    // interlayer bufA/bufB visibility (L2 wb + L1 inv)
    __syncthreads();
  } // l
}

extern "C" void kernel_launch(void* const* d_in, const int* in_sizes, int n_in,
                              void* d_out, int out_size, void* d_ws, size_t ws_size,
                              hipStream_t stream)
{
  const float* x  = (const float*)d_in[0];
  const float* W  = (const float*)d_in[1];
  const float* bb = (const float*)d_in[2];
  const float* Wa = (const float*)d_in[3];
  const float* ba = (const float*)d_in[4];
  float* out = (float*)d_out;
  f16* bufA = (f16*)d_ws;                         // [256 t][256 b][64] f16
  f16* bufB = bufA + (size_t)TT*256*64;           // ditto (16.8 MB total <= ws)

  hipLaunchKernelGGL(s2_mfma_kernel, dim3(16), dim3(512), 0, stream,
                     x, W, bb, Wa, ba, out, bufA, bufB);
}

// Round 5
// 548.366 us; speedup vs baseline: 5.7905x; 2.5031x over previous
//
#include <hip/hip_runtime.h>
#include <cmath>

#define TT 256
#define KD 192
#define RINGM 127   // 128-row ring for bufA/bufC

typedef _Float16 f16;
typedef _Float16 f16x4 __attribute__((ext_vector_type(4)));
typedef _Float16 f16x8 __attribute__((ext_vector_type(8)));
typedef float    f32x4 __attribute__((ext_vector_type(4)));
typedef unsigned int u32;

#define SWZ(b,k) ((k) ^ (((b)&7)<<3))
#define MFMA16(a,bb,c) __builtin_amdgcn_mfma_f32_16x16x32_f16((a),(bb),(c),0,0,0)

__device__ __forceinline__ float sigm(float x){
  return __builtin_amdgcn_rcpf(1.0f + __expf(-x));
}
__device__ __forceinline__ float ftanh(float x){
  x = fminf(15.0f, fmaxf(-15.0f, x));
  float e = __expf(-2.0f*x);
  return (1.0f - e) * __builtin_amdgcn_rcpf(1.0f + e);
}
// tag flags: entry c holds c+1 when ready; 0xAAAAAAAA poison never matches (c+1<=64)
__device__ __forceinline__ void waitflag(const u32* p, u32 v){
  while (__hip_atomic_load(p, __ATOMIC_ACQUIRE, __HIP_MEMORY_SCOPE_AGENT) != v)
    __builtin_amdgcn_s_sleep(2);
}
__device__ __forceinline__ void setflag(u32* p, u32 v){
  __hip_atomic_store(p, v, __ATOMIC_RELEASE, __HIP_MEMORY_SCOPE_AGENT);
}

// 64 blocks: blockIdx = l*16 + bg. Stage l runs layer l's 256 steps for its
// 16-batch group. Dataflow: l0 -> bufA(ring,f16) -> l1 -> d_out(f32) -> {l2, l3 skip}
//                           l2 -> bufC(ring,f16) -> l3 -> d_out (fused projection)
// fwd flags: rows ready; cons flags: ring back-pressure (consumer progress).
extern "C" __global__ void
__attribute__((amdgpu_flat_work_group_size(512,512), amdgpu_waves_per_eu(2,2)))
s2_pipe_kernel(const float* __restrict__ xin, const float* __restrict__ W,
               const float* __restrict__ bias, const float* __restrict__ Wa,
               const float* __restrict__ ba, float* __restrict__ out,
               f16* __restrict__ bufA, f16* __restrict__ bufC,
               u32* __restrict__ fwdf, u32* __restrict__ consf)
{
  const int tid  = threadIdx.x;
  const int wave = tid >> 6;
  const int lane = tid & 63;
  const int b    = lane & 15;          // batch within group (frag col)
  const int g4   = lane >> 4;
  const int bg   = blockIdx.x & 15;
  const int l    = blockIdx.x >> 4;
  const int gb   = bg*16 + b;          // global batch index
  const int s0   = wave*16 + g4*4;
  const int d    = (l==0)?1:((l==1)?3:((l==2)?6:12));

  __shared__ f16 sxh[2][16*KD];
  __shared__ f16 scb[12*16*128];
  __shared__ f16 shb[12*16*64];
  __shared__ f16 sfin[2][16*64];

  u32* fIn  = fwdf + (((l>0)?(l-1):0)*16 + bg)*64;   // poll (l>0)
  u32* fOut = fwdf + (((l<3)?l:0)*16 + bg)*64;       // publish (l<3)
  u32* cPub = consf + (((l==3)?1:0)*16 + bg)*64;     // publish (l1,l3)
  u32* cPol = consf + (((l==2)?1:0)*16 + bg)*64;     // poll (l0,l2)
  f16* ringOut       = (l==0) ? bufA : bufC;
  const f16* ringIn  = (l==1) ? bufA : bufC;

  // ---- projection frags (l==3, waves 0-3) ----
  f16x8 aP[2]; f32x4 cbP;
  if (l==3 && wave < 4) {
    #pragma unroll
    for (int kt=0;kt<2;++kt) {
      const float* p = Wa + (size_t)(wave*16 + b)*64 + kt*32 + g4*8;
      float4 lo = *(const float4*)p, hi = *(const float4*)(p+4);
      f16x8 v;
      v[0]=(f16)lo.x; v[1]=(f16)lo.y; v[2]=(f16)lo.z; v[3]=(f16)lo.w;
      v[4]=(f16)hi.x; v[5]=(f16)hi.y; v[6]=(f16)hi.z; v[7]=(f16)hi.w;
      aP[kt]=v;
    }
    float4 bb4 = *(const float4*)(ba + s0);
    cbP[0]=bb4.x; cbP[1]=bb4.y; cbP[2]=bb4.z; cbP[3]=bb4.w;
  }

  // ---- this layer's W frags + bias ----
  f16x8 aW[4][6]; f32x4 cb[4];
  const float* Wl = W + (size_t)l*512*KD;
  #pragma unroll
  for (int q=0;q<4;++q) {
    const float* pr = Wl + (size_t)(128*q + 16*wave + b)*KD + g4*8;
    #pragma unroll
    for (int kt=0;kt<6;++kt) {
      float4 lo = *(const float4*)(pr + kt*32);
      float4 hi = *(const float4*)(pr + kt*32 + 4);
      f16x8 v;
      v[0]=(f16)lo.x; v[1]=(f16)lo.y; v[2]=(f16)lo.z; v[3]=(f16)lo.w;
      v[4]=(f16)hi.x; v[5]=(f16)hi.y; v[6]=(f16)hi.z; v[7]=(f16)hi.w;
      aW[q][kt]=v;
    }
    float4 b4 = *(const float4*)(bias + l*512 + 128*q + s0);
    cb[q][0]=b4.x; cb[q][1]=b4.y; cb[q][2]=b4.z; cb[q][3]=b4.w;
  }

  // ---- init: stage xh(0) = [x0|0|0], prefetch row1 (+skip row0 for l3) ----
  float4 xAf, xBf, skA, skB; f16x4 xAh, xBh;
  if (wave >= 4) {
    f16x4 zz = {(f16)0,(f16)0,(f16)0,(f16)0};
    *(f16x4*)&sxh[0][b*KD + SWZ(b, s0)]    = zz;
    *(f16x4*)&sxh[0][b*KD + SWZ(b, s0+64)] = zz;
  } else {
    if (l>0) waitflag(&fIn[0], 1u);      // producer rows 0-3 ready
    if (l==0) {
      float4 v0 = *(const float4*)(xin + ((size_t)gb)*64 + s0);
      f16x4 h; h[0]=(f16)v0.x; h[1]=(f16)v0.y; h[2]=(f16)v0.z; h[3]=(f16)v0.w;
      *(f16x4*)&sxh[0][b*KD + SWZ(b, s0)] = h;
      xAf = *(const float4*)(xin + ((size_t)256 + gb)*64 + s0);
    } else if (l==2) {
      float4 v0 = *(const float4*)(out + ((size_t)gb)*64 + s0);
      f16x4 h; h[0]=(f16)v0.x; h[1]=(f16)v0.y; h[2]=(f16)v0.z; h[3]=(f16)v0.w;
      *(f16x4*)&sxh[0][b*KD + SWZ(b, s0)] = h;
      xAf = *(const float4*)(out + ((size_t)256 + gb)*64 + s0);
    } else { // l==1 or l==3: f16 ring input
      *(f16x4*)&sxh[0][b*KD + SWZ(b, s0)] =
          *(const f16x4*)(ringIn + ((size_t)0*256 + gb)*64 + s0);
      xAh = *(const f16x4*)(ringIn + ((size_t)1*256 + gb)*64 + s0);
      if (l==3) skA = *(const float4*)(out + ((size_t)gb)*64 + s0);
    }
  }
  float cpr[4] = {0.f,0.f,0.f,0.f};
  int idx = 0, ready = 0, consC = 0;
  __syncthreads();

  #pragma unroll 1
  for (int t=0; t<TT; ++t) {
    const int p = t & 1;
    const int idx2 = (idx+1==d) ? 0 : idx+1;

    // ---- B-frag reads of xh(t) ----
    f16x8 bx[6];
    const f16* xrow = &sxh[p][b*KD];
    #pragma unroll
    for (int kt=0;kt<6;++kt)
      bx[kt] = *(const f16x8*)&xrow[SWZ(b, kt*32 + g4*8)];

    // ---- early LDS reads (hide under MFMA) ----
    f16x4 dCv = *(const f16x4*)&scb[(idx*16+b)*128 + SWZ(b, s0)];
    f16x4 dhE;
    if (wave >= 4 && d > 1)
      dhE = *(const f16x4*)&shb[(idx2*16+b)*64 + SWZ(b, s0-64)];

    // ---- flag poll + prefetch + back-pressure (waves 0-3) ----
    if (wave < 4) {
      if (t+2 < TT) {
        int nc = (t+2) >> 2;
        if (l > 0 && nc > ready) { waitflag(&fIn[nc], (u32)(nc+1)); ready = nc; }
        if (l==0)      xBf = *(const float4*)(xin + ((size_t)(t+2)*256 + gb)*64 + s0);
        else if (l==2) xBf = *(const float4*)(out + ((size_t)(t+2)*256 + gb)*64 + s0);
        else           xBh = *(const f16x4*)(ringIn + ((size_t)((t+2)&RINGM)*256 + gb)*64 + s0);
      }
      if (l==3 && t+1 < TT) skB = *(const float4*)(out + ((size_t)(t+1)*256 + gb)*64 + s0);
      if ((l==0 || l==2) && (4*consC + 129 < t)) {      // ring overwrite guard
        int Ke = ((t-129+3)>>2) + 8; if (Ke > 64) Ke = 64;
        waitflag(&cPol[Ke-1], (u32)Ke);
        consC = Ke;
      }
    }

    // ---- fused projection for step t-1 (l==3) ----
    if (l==3 && wave < 4 && t > 0) {
      const f16* fr = &sfin[p^1][b*64];
      f16x8 b0 = *(const f16x8*)&fr[SWZ(b, g4*8)];
      f16x8 b1 = *(const f16x8*)&fr[SWZ(b, 32 + g4*8)];
      f32x4 pa = cbP;
      pa = MFMA16(aP[0], b0, pa);
      pa = MFMA16(aP[1], b1, pa);
      float4 st; st.x=pa[0]; st.y=pa[1]; st.z=pa[2]; st.w=pa[3];
      *(float4*)(out + ((size_t)(t-1)*256 + gb)*64 + s0) = st;
    }

    // ---- gate MFMA: gates = W . xh + bias ----
    f32x4 a0=cb[0], a1=cb[1], a2=cb[2], a3=cb[3];
    #pragma unroll
    for (int kt=0;kt<6;++kt) {
      a0 = MFMA16(aW[0][kt], bx[kt], a0);
      a1 = MFMA16(aW[1][kt], bx[kt], a1);
      a2 = MFMA16(aW[2][kt], bx[kt], a2);
      a3 = MFMA16(aW[3][kt], bx[kt], a3);
    }

    // ---- phase B: in-register LSTM update (4 cells/thread) ----
    float whole[4]; f16x4 ncv;
    #pragma unroll
    for (int r=0;r<4;++r) {
      float f  = sigm(a0[r] + 1.0f);
      float ns = ftanh(a1[r]);
      float al = sigm(a2[r]);
      float o  = sigm(a3[r]);
      float dC = (float)dCv[r];
      float wC = (t>=d) ? fmaf(al, cpr[r]-dC, dC) : cpr[r];
      float nc = (t>0)  ? fmaf(f, wC-ns, ns) : ns;
      whole[r] = o*nc; cpr[r] = nc; ncv[r] = (f16)nc;
    }
    *(f16x4*)&scb[(idx*16+b)*128 + SWZ(b, s0)] = ncv;

    if (wave >= 4) {
      const int jj = s0 - 64;
      f16x4 hv;
      #pragma unroll
      for (int r=0;r<4;++r) hv[r]=(f16)whole[r];
      *(f16x4*)&shb[(idx*16+b)*64 + SWZ(b, jj)] = hv;
      *(f16x4*)&sxh[p^1][b*KD + SWZ(b, s0)] = hv;           // prevH for t+1
      f16x4 dhv = hv;
      if (t+1 >= d && d > 1) dhv = dhE;                     // h_{t+1-d}
      *(f16x4*)&sxh[p^1][b*KD + SWZ(b, s0+64)] = dhv;       // dH for t+1
    } else {
      // out dims: emit layer output + stage x(t+1)
      f16x4 xv;
      if (l==0 || l==2) { xv[0]=(f16)xAf.x; xv[1]=(f16)xAf.y; xv[2]=(f16)xAf.z; xv[3]=(f16)xAf.w; xAf = xBf; }
      else              { xv = xAh; xAh = xBh; }
      *(f16x4*)&sxh[p^1][b*KD + SWZ(b, s0)] = xv;
      if (l==3) {
        f16x4 fv;
        #pragma unroll
        for (int r=0;r<4;++r) fv[r] = (f16)(whole[r] + ((const float*)&skA)[r]);
        *(f16x4*)&sfin[p][b*64 + SWZ(b, s0)] = fv;
        skA = skB;
      } else if (l==1) {
        float4 st; st.x=whole[0]; st.y=whole[1]; st.z=whole[2]; st.w=whole[3];
        *(float4*)(out + ((size_t)t*256 + gb)*64 + s0) = st;   // f32, pre-projection
      } else {
        f16x4 ov;
        #pragma unroll
        for (int r=0;r<4;++r) ov[r]=(f16)whole[r];
        *(f16x4*)(ringOut + ((size_t)(t&RINGM)*256 + gb)*64 + s0) = ov;
      }
    }
    idx = idx2;
    __syncthreads();   // drains stores (vmcnt0) -> safe to publish

    if ((t&3)==3 && tid==0) {
      if (l<3)            setflag(&fOut[t>>2], (u32)((t>>2)+1));  // rows<=t ready
      if (l==1 || l==3)   setflag(&cPub[t>>2], (u32)((t>>2)+1));  // ring consumed
    }
  } // t

  // epilogue projection for t = 255 (l==3)
  if (l==3 && wave < 4) {
    const f16* fr = &sfin[1][b*64];
    f16x8 b0 = *(const f16x8*)&fr[SWZ(b, g4*8)];
    f16x8 b1 = *(const f16x8*)&fr[SWZ(b, 32 + g4*8)];
    f32x4 pa = cbP;
    pa = MFMA16(aP[0], b0, pa);
    pa = MFMA16(aP[1], b1, pa);
    float4 st; st.x=pa[0]; st.y=pa[1]; st.z=pa[2]; st.w=pa[3];
    *(float4*)(out + ((size_t)(TT-1)*256 + gb)*64 + s0) = st;
  }
}

extern "C" void kernel_launch(void* const* d_in, const int* in_sizes, int n_in,
                              void* d_out, int out_size, void* d_ws, size_t ws_size,
                              hipStream_t stream)
{
  const float* x  = (const float*)d_in[0];
  const float* W  = (const float*)d_in[1];
  const float* bb = (const float*)d_in[2];
  const float* Wa = (const float*)d_in[3];
  const float* ba = (const float*)d_in[4];
  float* out = (float*)d_out;

  f16* bufA  = (f16*)d_ws;                                   // 4 MB ring (l0 out)
  f16* bufC  = (f16*)((char*)d_ws + (4u<<20));               // 4 MB ring (l2 out)
  u32* fwdf  = (u32*)((char*)d_ws + (8u<<20));               // 3*16*64 u32
  u32* consf = (u32*)((char*)d_ws + (8u<<20) + 3*16*64*4);   // 2*16*64 u32

  hipLaunchKernelGGL(s2_pipe_kernel, dim3(64), dim3(512), 0, stream,
                     x, W, bb, Wa, ba, out, bufA, bufC, fwdf, consf);
}